// Round 1
// baseline (1197.195 us; speedup 1.0000x reference)
//
#include <hip/hip_runtime.h>
#include <math.h>

#define D 128

// ---------------- graph preprocessing ----------------

__global__ __launch_bounds__(256) void k_zero(int* __restrict__ p, int n) {
  int i = blockIdx.x * 256 + threadIdx.x;
  if (i < n) p[i] = 0;
}

__global__ __launch_bounds__(256) void k_hist(const int* __restrict__ dst,
                                              int* __restrict__ counts, int E) {
  int e = blockIdx.x * 256 + threadIdx.x;
  if (e < E) atomicAdd(&counts[dst[e]], 1);
}

// block of 256 threads scans 1024 elements; writes per-element exclusive
// prefix (within block) and the block total.
__global__ __launch_bounds__(256) void k_scan1(const int* __restrict__ in,
                                               int* __restrict__ out,
                                               int* __restrict__ bsum, int n) {
  __shared__ int sd[256];
  int tid = threadIdx.x;
  int base = blockIdx.x * 1024 + tid * 4;
  int v0 = 0, v1 = 0, v2 = 0, v3 = 0;
  if (base + 3 < n) {
    int4 t = *(const int4*)(in + base);
    v0 = t.x; v1 = t.y; v2 = t.z; v3 = t.w;
  } else {
    if (base     < n) v0 = in[base];
    if (base + 1 < n) v1 = in[base + 1];
    if (base + 2 < n) v2 = in[base + 2];
    if (base + 3 < n) v3 = in[base + 3];
  }
  int s = v0 + v1 + v2 + v3;
  sd[tid] = s;
  __syncthreads();
  for (int off = 1; off < 256; off <<= 1) {
    int t = (tid >= off) ? sd[tid - off] : 0;
    __syncthreads();
    sd[tid] += t;
    __syncthreads();
  }
  int incl = sd[tid];
  int excl = incl - s;
  if (tid == 255) bsum[blockIdx.x] = incl;
  int r = excl;
  if (base     < n) out[base]     = r; r += v0;
  if (base + 1 < n) out[base + 1] = r; r += v1;
  if (base + 2 < n) out[base + 2] = r; r += v2;
  if (base + 3 < n) out[base + 3] = r;
}

// single block: exclusive scan of block sums (nb <= 256)
__global__ __launch_bounds__(256) void k_scan2(int* __restrict__ bsum, int nb) {
  __shared__ int sd[256];
  int tid = threadIdx.x;
  int v = (tid < nb) ? bsum[tid] : 0;
  sd[tid] = v;
  __syncthreads();
  for (int off = 1; off < 256; off <<= 1) {
    int t = (tid >= off) ? sd[tid - off] : 0;
    __syncthreads();
    sd[tid] += t;
    __syncthreads();
  }
  int excl = sd[tid] - v;
  if (tid < nb) bsum[tid] = excl;
}

// rowptr += block offset; init cursor; dis = rsqrt(deg) with deg = counts+1
__global__ __launch_bounds__(256) void k_finish(int* __restrict__ rowptr,
                                                int* __restrict__ cursor,
                                                float* __restrict__ dis,
                                                const int* __restrict__ counts,
                                                const int* __restrict__ bsum, int n) {
  int i = blockIdx.x * 256 + threadIdx.x;
  if (i < n) {
    int r = rowptr[i] + bsum[i >> 10];
    rowptr[i] = r;
    cursor[i] = r;
    dis[i] = rsqrtf((float)(counts[i] + 1));
  }
}

__global__ __launch_bounds__(256) void k_fill(const int* __restrict__ src,
                                              const int* __restrict__ dst,
                                              int* __restrict__ cursor,
                                              const float* __restrict__ dis,
                                              int* __restrict__ csrc,
                                              float* __restrict__ cnorm, int E) {
  int e = blockIdx.x * 256 + threadIdx.x;
  if (e < E) {
    int s = src[e], d = dst[e];
    int pos = atomicAdd(&cursor[d], 1);
    csrc[pos] = s;
    cnorm[pos] = dis[s] * dis[d];
  }
}

// ---------------- fp32 GEMM: Y = X @ W (+bias, +ELU) ----------------
// X: n x 128, W: 128 x 128 row-major, Y: n x 128.
// Block: 256 threads, 32 rows. Thread (tx,ty) computes rows ty*4..+3, cols tx*4..+3.

__device__ __forceinline__ float elu1(float x) {
  return x > 0.f ? x : (expf(x) - 1.f);
}

__global__ __launch_bounds__(256) void k_gemm(const float* __restrict__ X,
                                              const float* __restrict__ W,
                                              const float* __restrict__ bias,
                                              float* __restrict__ Y, int n, int act) {
  __shared__ float xs[32][132];   // [row][k], padded to 132 (float4-aligned rows)
  __shared__ float ws[64 * 128];  // [k][c] half of W
  int tid = threadIdx.x;
  size_t row0 = (size_t)blockIdx.x * 32;

  // load X tile (32x128 floats = 1024 float4), coalesced
  const float4* X4 = (const float4*)(X + row0 * D);
  float4 zero4 = make_float4(0.f, 0.f, 0.f, 0.f);
#pragma unroll
  for (int i = 0; i < 4; i++) {
    int idx = tid + i * 256;          // float4 index: row = idx>>5, k4 = idx&31
    int r = idx >> 5, k4 = idx & 31;
    float4 v = ((long)(row0 + r) < n) ? X4[idx] : zero4;
    *(float4*)&xs[r][k4 * 4] = v;     // consecutive 16B per lane: conflict-free
  }

  int tx = tid & 31, ty = tid >> 5;
  int c0 = tx * 4, r0 = ty * 4;
  float4 a0c = zero4, a1c = zero4, a2c = zero4, a3c = zero4;

  for (int h = 0; h < 2; h++) {
    __syncthreads();  // protects xs (h=0) and ws reuse (h=1)
    const float4* W4 = (const float4*)(W + (size_t)h * 64 * D);
    float4* ws4 = (float4*)ws;
#pragma unroll
    for (int i = 0; i < 8; i++) ws4[tid + i * 256] = W4[tid + i * 256];
    __syncthreads();
    int kb = h * 64;
#pragma unroll 4
    for (int k = 0; k < 64; k++) {
      float4 b = *(const float4*)&ws[k * D + c0];
      float a0 = xs[r0 + 0][kb + k];
      float a1 = xs[r0 + 1][kb + k];
      float a2 = xs[r0 + 2][kb + k];
      float a3 = xs[r0 + 3][kb + k];
      a0c.x += a0 * b.x; a0c.y += a0 * b.y; a0c.z += a0 * b.z; a0c.w += a0 * b.w;
      a1c.x += a1 * b.x; a1c.y += a1 * b.y; a1c.z += a1 * b.z; a1c.w += a1 * b.w;
      a2c.x += a2 * b.x; a2c.y += a2 * b.y; a2c.z += a2 * b.z; a2c.w += a2 * b.w;
      a3c.x += a3 * b.x; a3c.y += a3 * b.y; a3c.z += a3 * b.z; a3c.w += a3 * b.w;
    }
  }

  float4 bb = bias ? *(const float4*)&bias[c0] : zero4;
  float4 accs[4] = {a0c, a1c, a2c, a3c};
#pragma unroll
  for (int i = 0; i < 4; i++) {
    long row = (long)(row0 + r0 + i);
    if (row < n) {
      float4 o = accs[i];
      o.x += bb.x; o.y += bb.y; o.z += bb.z; o.w += bb.w;
      if (act == 1) { o.x = elu1(o.x); o.y = elu1(o.y); o.z = elu1(o.z); o.w = elu1(o.w); }
      *(float4*)&Y[row * D + c0] = o;
    }
  }
}

// ---------------- aggregation: Y[d] = relu(sum_{e: dst=d} T[src]*norm + T[d]*dis[d]^2 + b) ----
// one block (128 threads) per node; thread = feature

__global__ __launch_bounds__(128) void k_agg(const float* __restrict__ T,
                                             const int* __restrict__ rowptr,
                                             const int* __restrict__ counts,
                                             const int* __restrict__ csrc,
                                             const float* __restrict__ cnorm,
                                             const float* __restrict__ dis,
                                             const float* __restrict__ bias,
                                             float* __restrict__ Y, int n) {
  int node = blockIdx.x;
  if (node >= n) return;
  int f = threadIdx.x;
  int s = rowptr[node];
  int e = s + counts[node];
  float dv = dis[node];
  float acc = T[(size_t)node * D + f] * (dv * dv);  // self-loop message
  for (int j = s; j < e; ++j) {
    int sn = csrc[j];
    float nw = cnorm[j];
    acc += T[(size_t)sn * D + f] * nw;
  }
  acc += bias[f];
  Y[(size_t)node * D + f] = fmaxf(acc, 0.f);
}

// ---------------- MLP head: logits = m @ Wm2 + b; probs = softmax ----------------
// one wave (64 lanes) per node; lanes 0..39 own the 40 output classes

__global__ __launch_bounds__(256) void k_head(const float* __restrict__ M,
                                              const float* __restrict__ W,
                                              const float* __restrict__ b,
                                              float* __restrict__ logits,
                                              float* __restrict__ probs, int n) {
  int node = (blockIdx.x * 256 + threadIdx.x) >> 6;
  int lane = threadIdx.x & 63;
  if (node >= n) return;
  const float* m = M + (size_t)node * D;
  float m0 = m[lane];
  float m1 = m[lane + 64];
  int col = lane < 40 ? lane : 39;
  float acc = b[col];
#pragma unroll 8
  for (int k = 0; k < 64; k++) acc += __shfl(m0, k) * W[k * 40 + col];
#pragma unroll 8
  for (int k = 0; k < 64; k++) acc += __shfl(m1, k) * W[(64 + k) * 40 + col];
  float v = (lane < 40) ? acc : -INFINITY;
  for (int off = 32; off; off >>= 1) v = fmaxf(v, __shfl_xor(v, off));
  float ex = (lane < 40) ? expf(acc - v) : 0.f;
  float sum = ex;
  for (int off = 32; off; off >>= 1) sum += __shfl_xor(sum, off);
  float inv = 1.f / sum;
  if (lane < 40) {
    logits[(size_t)node * 40 + lane] = acc;
    probs[(size_t)node * 40 + lane] = ex * inv;
  }
}

// ---------------- launcher ----------------

extern "C" void kernel_launch(void* const* d_in, const int* in_sizes, int n_in,
                              void* d_out, int out_size, void* d_ws, size_t ws_size,
                              hipStream_t stream) {
  const float* x   = (const float*)d_in[0];
  const int*   ei  = (const int*)d_in[1];
  const float* W1  = (const float*)d_in[2];
  const float* b1  = (const float*)d_in[3];
  const float* W2  = (const float*)d_in[4];
  const float* b2  = (const float*)d_in[5];
  const float* W3  = (const float*)d_in[6];
  const float* b3  = (const float*)d_in[7];
  const float* Wm1 = (const float*)d_in[8];
  const float* bm1 = (const float*)d_in[9];
  const float* Wm2 = (const float*)d_in[10];
  const float* bm2 = (const float*)d_in[11];

  int N = in_sizes[0] / D;
  int E = in_sizes[1] / 2;
  const int* srcp = ei;
  const int* dstp = ei + E;

  char* w = (char*)d_ws;
  auto alloc = [&](size_t bytes) -> char* {
    char* p = w;
    w += (bytes + 255) & ~(size_t)255;
    return p;
  };
  int*   counts = (int*)alloc((size_t)N * 4);
  int*   rowptr = (int*)alloc((size_t)N * 4);
  int*   cursor = (int*)alloc((size_t)N * 4);
  float* dis    = (float*)alloc((size_t)N * 4);
  int*   bsum   = (int*)alloc(1024);
  int*   csrc   = (int*)alloc((size_t)E * 4);
  float* cnorm  = (float*)alloc((size_t)E * 4);
  float* tmp    = (float*)alloc((size_t)N * D * 4);
  float* hbuf   = (float*)alloc((size_t)N * D * 4);

  float* logits = (float*)d_out;
  float* probs  = logits + (size_t)N * 40;
  float* emb    = probs + (size_t)N * 40;

  // CSR build (edges identical for all 3 layers)
  k_zero<<<(N + 255) / 256, 256, 0, stream>>>(counts, N);
  k_hist<<<(E + 255) / 256, 256, 0, stream>>>(dstp, counts, E);
  int nb = (N + 1023) / 1024;
  k_scan1<<<nb, 256, 0, stream>>>(counts, rowptr, bsum, N);
  k_scan2<<<1, 256, 0, stream>>>(bsum, nb);
  k_finish<<<(N + 255) / 256, 256, 0, stream>>>(rowptr, cursor, dis, counts, bsum, N);
  k_fill<<<(E + 255) / 256, 256, 0, stream>>>(srcp, dstp, cursor, dis, csrc, cnorm, E);

  int gblocks = (N + 31) / 32;
  // layer 1
  k_gemm<<<gblocks, 256, 0, stream>>>(x, W1, nullptr, tmp, N, 0);
  k_agg<<<N, 128, 0, stream>>>(tmp, rowptr, counts, csrc, cnorm, dis, b1, hbuf, N);
  // layer 2
  k_gemm<<<gblocks, 256, 0, stream>>>(hbuf, W2, nullptr, tmp, N, 0);
  k_agg<<<N, 128, 0, stream>>>(tmp, rowptr, counts, csrc, cnorm, dis, b2, hbuf, N);
  // layer 3 -> emb (in d_out)
  k_gemm<<<gblocks, 256, 0, stream>>>(hbuf, W3, nullptr, tmp, N, 0);
  k_agg<<<N, 128, 0, stream>>>(tmp, rowptr, counts, csrc, cnorm, dis, b3, emb, N);
  // MLP head
  k_gemm<<<gblocks, 256, 0, stream>>>(emb, Wm1, bm1, tmp, N, 1);
  k_head<<<(N * 64 + 255) / 256, 256, 0, stream>>>(tmp, Wm2, bm2, logits, probs, N);
}

// Round 2
// 1021.723 us; speedup vs baseline: 1.1717x; 1.1717x over previous
//
#include <hip/hip_runtime.h>
#include <math.h>

#define D 128

typedef __attribute__((ext_vector_type(8))) short short8;
typedef __attribute__((ext_vector_type(4))) float floatx4;

// ---------------- graph preprocessing ----------------

__global__ __launch_bounds__(256) void k_zero(int* __restrict__ p, int n) {
  int i = blockIdx.x * 256 + threadIdx.x;
  if (i < n) p[i] = 0;
}

__global__ __launch_bounds__(256) void k_hist(const int* __restrict__ dst,
                                              int* __restrict__ counts, int E) {
  int e = blockIdx.x * 256 + threadIdx.x;
  if (e < E) atomicAdd(&counts[dst[e]], 1);
}

__global__ __launch_bounds__(256) void k_scan1(const int* __restrict__ in,
                                               int* __restrict__ out,
                                               int* __restrict__ bsum, int n) {
  __shared__ int sd[256];
  int tid = threadIdx.x;
  int base = blockIdx.x * 1024 + tid * 4;
  int v0 = 0, v1 = 0, v2 = 0, v3 = 0;
  if (base + 3 < n) {
    int4 t = *(const int4*)(in + base);
    v0 = t.x; v1 = t.y; v2 = t.z; v3 = t.w;
  } else {
    if (base     < n) v0 = in[base];
    if (base + 1 < n) v1 = in[base + 1];
    if (base + 2 < n) v2 = in[base + 2];
    if (base + 3 < n) v3 = in[base + 3];
  }
  int s = v0 + v1 + v2 + v3;
  sd[tid] = s;
  __syncthreads();
  for (int off = 1; off < 256; off <<= 1) {
    int t = (tid >= off) ? sd[tid - off] : 0;
    __syncthreads();
    sd[tid] += t;
    __syncthreads();
  }
  int incl = sd[tid];
  int excl = incl - s;
  if (tid == 255) bsum[blockIdx.x] = incl;
  int r = excl;
  if (base     < n) out[base]     = r; r += v0;
  if (base + 1 < n) out[base + 1] = r; r += v1;
  if (base + 2 < n) out[base + 2] = r; r += v2;
  if (base + 3 < n) out[base + 3] = r;
}

__global__ __launch_bounds__(256) void k_scan2(int* __restrict__ bsum, int nb) {
  __shared__ int sd[256];
  int tid = threadIdx.x;
  int v = (tid < nb) ? bsum[tid] : 0;
  sd[tid] = v;
  __syncthreads();
  for (int off = 1; off < 256; off <<= 1) {
    int t = (tid >= off) ? sd[tid - off] : 0;
    __syncthreads();
    sd[tid] += t;
    __syncthreads();
  }
  int excl = sd[tid] - v;
  if (tid < nb) bsum[tid] = excl;
}

__global__ __launch_bounds__(256) void k_finish(int* __restrict__ rowptr,
                                                int* __restrict__ cursor,
                                                float* __restrict__ dis,
                                                const int* __restrict__ counts,
                                                const int* __restrict__ bsum, int n) {
  int i = blockIdx.x * 256 + threadIdx.x;
  if (i < n) {
    int r = rowptr[i] + bsum[i >> 10];
    rowptr[i] = r;
    cursor[i] = r;
    dis[i] = rsqrtf((float)(counts[i] + 1));
  }
}

__global__ __launch_bounds__(256) void k_fill(const int* __restrict__ src,
                                              const int* __restrict__ dst,
                                              int* __restrict__ cursor,
                                              const float* __restrict__ dis,
                                              int* __restrict__ csrc,
                                              float* __restrict__ cnorm, int E) {
  int e = blockIdx.x * 256 + threadIdx.x;
  if (e < E) {
    int s = src[e], d = dst[e];
    int pos = atomicAdd(&cursor[d], 1);
    csrc[pos] = s;
    cnorm[pos] = dis[s] * dis[d];
  }
}

// ---------------- bf16x4-split MFMA GEMM: Y = X @ W (+bias, +ELU) ----------------
// X: n x 128 fp32, W: 128 x 128 fp32 row-major.
// Split both into bf16 hi/lo; 4 MFMAs reconstruct fp32 product (~2^-17 rel err).
// Block 256 thr = 4 waves; wave owns 32 rows (2 row-tiles of 16); block = 128 rows.
// W^T staged in LDS (bf16 hi/lo) half-K at a time: wt[c][k], stride 72 (pad 8).

__device__ __forceinline__ short f2bf(float v) {
  unsigned u = __float_as_uint(v);
  unsigned r = (u + 0x7FFFu + ((u >> 16) & 1u)) >> 16;
  return (short)r;
}
__device__ __forceinline__ float bf2f(short s) {
  return __uint_as_float(((unsigned)(unsigned short)s) << 16);
}

__device__ __forceinline__ float elu1(float x) {
  return x > 0.f ? x : (expf(x) - 1.f);
}

__global__ __launch_bounds__(256, 2) void k_gemm(const float* __restrict__ X,
                                                 const float* __restrict__ W,
                                                 const float* __restrict__ bias,
                                                 float* __restrict__ Y, int n, int act) {
  __shared__ short wthi[128 * 72];  // [c][k-half], padded stride 72
  __shared__ short wtlo[128 * 72];

  int tid = threadIdx.x;
  int wave = tid >> 6, lane = tid & 63;
  int q = lane >> 4, r = lane & 15;

  long rowbase = (long)blockIdx.x * 128 + wave * 32;
  long row0 = rowbase + r;        // row-tile 0
  long row1 = rowbase + 16 + r;   // row-tile 1
  long rc0 = row0 < n ? row0 : (n - 1);
  long rc1 = row1 < n ? row1 : (n - 1);
  const floatx4* x0 = (const floatx4*)(X + rc0 * D);
  const floatx4* x1 = (const floatx4*)(X + rc1 * D);

  floatx4 acc[2][8];
#pragma unroll
  for (int rt = 0; rt < 2; rt++)
#pragma unroll
    for (int ct = 0; ct < 8; ct++) acc[rt][ct] = (floatx4){0.f, 0.f, 0.f, 0.f};

  const floatx4* W4 = (const floatx4*)W;

  for (int h = 0; h < 2; h++) {
    __syncthreads();
    // stage W rows [h*64, h*64+64) transposed as bf16 hi/lo
#pragma unroll
    for (int i = 0; i < 8; i++) {
      int idx4 = i * 256 + tid;            // 2048 float4 = 8192 floats
      int kk = idx4 >> 5;                  // 0..63
      int c4 = (idx4 & 31) * 4;
      floatx4 w = W4[h * 2048 + idx4];
#pragma unroll
      for (int m = 0; m < 4; m++) {
        float v = w[m];
        short hi = f2bf(v);
        short lo = f2bf(v - bf2f(hi));
        wthi[(c4 + m) * 72 + kk] = hi;
        wtlo[(c4 + m) * 72 + kk] = lo;
      }
    }
    __syncthreads();

#pragma unroll
    for (int ks = 0; ks < 2; ks++) {
      int kk0 = ks * 32;                    // k offset within half
      // A fragments: 8 consecutive fp32 along k per lane, per row-tile
      int xi = h * 16 + kk0 / 4 + q * 2;    // float4 index into row
      floatx4 a0 = x0[xi], a0b = x0[xi + 1];
      floatx4 a1 = x1[xi], a1b = x1[xi + 1];
      short8 ahi0, alo0, ahi1, alo1;
#pragma unroll
      for (int j = 0; j < 4; j++) {
        float v = a0[j];  short hi = f2bf(v);
        ahi0[j] = hi; alo0[j] = f2bf(v - bf2f(hi));
        v = a0b[j]; hi = f2bf(v);
        ahi0[4 + j] = hi; alo0[4 + j] = f2bf(v - bf2f(hi));
        v = a1[j];  hi = f2bf(v);
        ahi1[j] = hi; alo1[j] = f2bf(v - bf2f(hi));
        v = a1b[j]; hi = f2bf(v);
        ahi1[4 + j] = hi; alo1[4 + j] = f2bf(v - bf2f(hi));
      }
#pragma unroll
      for (int ct = 0; ct < 8; ct++) {
        int c = ct * 16 + r;
        short8 bh = *(const short8*)&wthi[c * 72 + kk0 + q * 8];
        short8 bl = *(const short8*)&wtlo[c * 72 + kk0 + q * 8];
        acc[0][ct] = __builtin_amdgcn_mfma_f32_16x16x32_bf16(ahi0, bh, acc[0][ct], 0, 0, 0);
        acc[0][ct] = __builtin_amdgcn_mfma_f32_16x16x32_bf16(ahi0, bl, acc[0][ct], 0, 0, 0);
        acc[0][ct] = __builtin_amdgcn_mfma_f32_16x16x32_bf16(alo0, bh, acc[0][ct], 0, 0, 0);
        acc[0][ct] = __builtin_amdgcn_mfma_f32_16x16x32_bf16(alo0, bl, acc[0][ct], 0, 0, 0);
        acc[1][ct] = __builtin_amdgcn_mfma_f32_16x16x32_bf16(ahi1, bh, acc[1][ct], 0, 0, 0);
        acc[1][ct] = __builtin_amdgcn_mfma_f32_16x16x32_bf16(ahi1, bl, acc[1][ct], 0, 0, 0);
        acc[1][ct] = __builtin_amdgcn_mfma_f32_16x16x32_bf16(alo1, bh, acc[1][ct], 0, 0, 0);
        acc[1][ct] = __builtin_amdgcn_mfma_f32_16x16x32_bf16(alo1, bl, acc[1][ct], 0, 0, 0);
      }
    }
  }

  // epilogue: C/D layout col = lane&15, row = q*4 + reg
#pragma unroll
  for (int rt = 0; rt < 2; rt++) {
#pragma unroll
    for (int i = 0; i < 4; i++) {
      long row = rowbase + rt * 16 + q * 4 + i;
      if (row < n) {
#pragma unroll
        for (int ct = 0; ct < 8; ct++) {
          int col = ct * 16 + r;
          float v = acc[rt][ct][i];
          if (bias) v += bias[col];
          if (act == 1) v = elu1(v);
          Y[row * D + col] = v;
        }
      }
    }
  }
}

// ---------------- aggregation ----------------
// Y[d] = relu(sum_{e: dst=d} T[src]*norm + T[d]*dis[d]^2 + b)
// one wave per node, float2 per lane, edge loop unrolled x4 (4 gathers in flight)

__global__ __launch_bounds__(256) void k_agg(const float* __restrict__ T,
                                             const int* __restrict__ rowptr,
                                             const int* __restrict__ counts,
                                             const int* __restrict__ csrc,
                                             const float* __restrict__ cnorm,
                                             const float* __restrict__ dis,
                                             const float* __restrict__ bias,
                                             float* __restrict__ Y, int n) {
  int node = blockIdx.x * 4 + (threadIdx.x >> 6);
  if (node >= n) return;
  int lane = threadIdx.x & 63;
  const float2* T2 = (const float2*)T;

  int s = rowptr[node];
  int e = s + counts[node];
  float dv = dis[node];
  float2 t = T2[(size_t)node * 64 + lane];
  float ax = t.x * (dv * dv), ay = t.y * (dv * dv);
  float bx2 = 0.f, by2 = 0.f, cx = 0.f, cy = 0.f, dx = 0.f, dy = 0.f;

  int j = s;
  for (; j + 3 < e; j += 4) {
    int s0 = csrc[j], s1 = csrc[j + 1], s2 = csrc[j + 2], s3 = csrc[j + 3];
    float n0 = cnorm[j], n1 = cnorm[j + 1], n2 = cnorm[j + 2], n3 = cnorm[j + 3];
    float2 v0 = T2[(size_t)s0 * 64 + lane];
    float2 v1 = T2[(size_t)s1 * 64 + lane];
    float2 v2 = T2[(size_t)s2 * 64 + lane];
    float2 v3 = T2[(size_t)s3 * 64 + lane];
    ax  += v0.x * n0; ay  += v0.y * n0;
    bx2 += v1.x * n1; by2 += v1.y * n1;
    cx  += v2.x * n2; cy  += v2.y * n2;
    dx  += v3.x * n3; dy  += v3.y * n3;
  }
  for (; j < e; ++j) {
    int s0 = csrc[j];
    float n0 = cnorm[j];
    float2 v0 = T2[(size_t)s0 * 64 + lane];
    ax += v0.x * n0; ay += v0.y * n0;
  }

  const float2* b2p = (const float2*)bias;
  float2 bb = b2p[lane];
  float rx = (ax + bx2) + (cx + dx) + bb.x;
  float ry = (ay + by2) + (cy + dy) + bb.y;
  float2 o;
  o.x = fmaxf(rx, 0.f);
  o.y = fmaxf(ry, 0.f);
  *(float2*)&Y[(size_t)node * D + lane * 2] = o;
}

// ---------------- MLP head ----------------

__global__ __launch_bounds__(256) void k_head(const float* __restrict__ M,
                                              const float* __restrict__ W,
                                              const float* __restrict__ b,
                                              float* __restrict__ logits,
                                              float* __restrict__ probs, int n) {
  int node = (blockIdx.x * 256 + threadIdx.x) >> 6;
  int lane = threadIdx.x & 63;
  if (node >= n) return;
  const float* m = M + (size_t)node * D;
  float m0 = m[lane];
  float m1 = m[lane + 64];
  int col = lane < 40 ? lane : 39;
  float acc = b[col];
#pragma unroll 8
  for (int k = 0; k < 64; k++) acc += __shfl(m0, k) * W[k * 40 + col];
#pragma unroll 8
  for (int k = 0; k < 64; k++) acc += __shfl(m1, k) * W[(64 + k) * 40 + col];
  float v = (lane < 40) ? acc : -INFINITY;
  for (int off = 32; off; off >>= 1) v = fmaxf(v, __shfl_xor(v, off));
  float ex = (lane < 40) ? expf(acc - v) : 0.f;
  float sum = ex;
  for (int off = 32; off; off >>= 1) sum += __shfl_xor(sum, off);
  float inv = 1.f / sum;
  if (lane < 40) {
    logits[(size_t)node * 40 + lane] = acc;
    probs[(size_t)node * 40 + lane] = ex * inv;
  }
}

// ---------------- launcher ----------------

extern "C" void kernel_launch(void* const* d_in, const int* in_sizes, int n_in,
                              void* d_out, int out_size, void* d_ws, size_t ws_size,
                              hipStream_t stream) {
  const float* x   = (const float*)d_in[0];
  const int*   ei  = (const int*)d_in[1];
  const float* W1  = (const float*)d_in[2];
  const float* b1  = (const float*)d_in[3];
  const float* W2  = (const float*)d_in[4];
  const float* b2  = (const float*)d_in[5];
  const float* W3  = (const float*)d_in[6];
  const float* b3  = (const float*)d_in[7];
  const float* Wm1 = (const float*)d_in[8];
  const float* bm1 = (const float*)d_in[9];
  const float* Wm2 = (const float*)d_in[10];
  const float* bm2 = (const float*)d_in[11];

  int N = in_sizes[0] / D;
  int E = in_sizes[1] / 2;
  const int* srcp = ei;
  const int* dstp = ei + E;

  char* w = (char*)d_ws;
  auto alloc = [&](size_t bytes) -> char* {
    char* p = w;
    w += (bytes + 255) & ~(size_t)255;
    return p;
  };
  int*   counts = (int*)alloc((size_t)N * 4);
  int*   rowptr = (int*)alloc((size_t)N * 4);
  int*   cursor = (int*)alloc((size_t)N * 4);
  float* dis    = (float*)alloc((size_t)N * 4);
  int*   bsum   = (int*)alloc(1024);
  int*   csrc   = (int*)alloc((size_t)E * 4);
  float* cnorm  = (float*)alloc((size_t)E * 4);
  float* tmp    = (float*)alloc((size_t)N * D * 4);
  float* hbuf   = (float*)alloc((size_t)N * D * 4);

  float* logits = (float*)d_out;
  float* probs  = logits + (size_t)N * 40;
  float* emb    = probs + (size_t)N * 40;

  // CSR build
  k_zero<<<(N + 255) / 256, 256, 0, stream>>>(counts, N);
  k_hist<<<(E + 255) / 256, 256, 0, stream>>>(dstp, counts, E);
  int nb = (N + 1023) / 1024;
  k_scan1<<<nb, 256, 0, stream>>>(counts, rowptr, bsum, N);
  k_scan2<<<1, 256, 0, stream>>>(bsum, nb);
  k_finish<<<(N + 255) / 256, 256, 0, stream>>>(rowptr, cursor, dis, counts, bsum, N);
  k_fill<<<(E + 255) / 256, 256, 0, stream>>>(srcp, dstp, cursor, dis, csrc, cnorm, E);

  int gblocks = (N + 127) / 128;
  int ablocks = (N + 3) / 4;
  // layer 1
  k_gemm<<<gblocks, 256, 0, stream>>>(x, W1, nullptr, tmp, N, 0);
  k_agg<<<ablocks, 256, 0, stream>>>(tmp, rowptr, counts, csrc, cnorm, dis, b1, hbuf, N);
  // layer 2
  k_gemm<<<gblocks, 256, 0, stream>>>(hbuf, W2, nullptr, tmp, N, 0);
  k_agg<<<ablocks, 256, 0, stream>>>(tmp, rowptr, counts, csrc, cnorm, dis, b2, hbuf, N);
  // layer 3 -> emb
  k_gemm<<<gblocks, 256, 0, stream>>>(hbuf, W3, nullptr, tmp, N, 0);
  k_agg<<<ablocks, 256, 0, stream>>>(tmp, rowptr, counts, csrc, cnorm, dis, b3, emb, N);
  // MLP head
  k_gemm<<<gblocks, 256, 0, stream>>>(emb, Wm1, bm1, tmp, N, 1);
  k_head<<<(N * 64 + 255) / 256, 256, 0, stream>>>(tmp, Wm2, bm2, logits, probs, N);
}

// Round 3
// 842.568 us; speedup vs baseline: 1.4209x; 1.2126x over previous
//
#include <hip/hip_runtime.h>
#include <math.h>

#define D 128

typedef __attribute__((ext_vector_type(8))) short short8;
typedef __attribute__((ext_vector_type(4))) float floatx4;

// ---------------- graph preprocessing ----------------

__global__ __launch_bounds__(256) void k_zero(int* __restrict__ p, int n) {
  int i = blockIdx.x * 256 + threadIdx.x;
  if (i < n) p[i] = 0;
}

__global__ __launch_bounds__(256) void k_hist(const int* __restrict__ dst,
                                              int* __restrict__ counts, int E) {
  int e = blockIdx.x * 256 + threadIdx.x;
  if (e < E) atomicAdd(&counts[dst[e]], 1);
}

__global__ __launch_bounds__(256) void k_scan1(const int* __restrict__ in,
                                               int* __restrict__ out,
                                               int* __restrict__ bsum, int n) {
  __shared__ int sd[256];
  int tid = threadIdx.x;
  int base = blockIdx.x * 1024 + tid * 4;
  int v0 = 0, v1 = 0, v2 = 0, v3 = 0;
  if (base + 3 < n) {
    int4 t = *(const int4*)(in + base);
    v0 = t.x; v1 = t.y; v2 = t.z; v3 = t.w;
  } else {
    if (base     < n) v0 = in[base];
    if (base + 1 < n) v1 = in[base + 1];
    if (base + 2 < n) v2 = in[base + 2];
    if (base + 3 < n) v3 = in[base + 3];
  }
  int s = v0 + v1 + v2 + v3;
  sd[tid] = s;
  __syncthreads();
  for (int off = 1; off < 256; off <<= 1) {
    int t = (tid >= off) ? sd[tid - off] : 0;
    __syncthreads();
    sd[tid] += t;
    __syncthreads();
  }
  int incl = sd[tid];
  int excl = incl - s;
  if (tid == 255) bsum[blockIdx.x] = incl;
  int r = excl;
  if (base     < n) out[base]     = r; r += v0;
  if (base + 1 < n) out[base + 1] = r; r += v1;
  if (base + 2 < n) out[base + 2] = r; r += v2;
  if (base + 3 < n) out[base + 3] = r;
}

__global__ __launch_bounds__(256) void k_scan2(int* __restrict__ bsum, int nb) {
  __shared__ int sd[256];
  int tid = threadIdx.x;
  int v = (tid < nb) ? bsum[tid] : 0;
  sd[tid] = v;
  __syncthreads();
  for (int off = 1; off < 256; off <<= 1) {
    int t = (tid >= off) ? sd[tid - off] : 0;
    __syncthreads();
    sd[tid] += t;
    __syncthreads();
  }
  int excl = sd[tid] - v;
  if (tid < nb) bsum[tid] = excl;
}

__global__ __launch_bounds__(256) void k_finish(int* __restrict__ rowptr,
                                                int* __restrict__ cursor,
                                                float* __restrict__ dis,
                                                const int* __restrict__ counts,
                                                const int* __restrict__ bsum, int n) {
  int i = blockIdx.x * 256 + threadIdx.x;
  if (i < n) {
    int r = rowptr[i] + bsum[i >> 10];
    rowptr[i] = r;
    cursor[i] = r;
    dis[i] = rsqrtf((float)(counts[i] + 1));
  }
}

__global__ __launch_bounds__(256) void k_fill(const int* __restrict__ src,
                                              const int* __restrict__ dst,
                                              int* __restrict__ cursor,
                                              const float* __restrict__ dis,
                                              int* __restrict__ csrc,
                                              float* __restrict__ cnorm, int E) {
  int e = blockIdx.x * 256 + threadIdx.x;
  if (e < E) {
    int s = src[e], d = dst[e];
    int pos = atomicAdd(&cursor[d], 1);
    csrc[pos] = s;
    cnorm[pos] = dis[s] * dis[d];
  }
}

// ---------------- weight pre-split (once per call) ----------------
// For W1,W2,W3,Wm1 (128x128): per half h, image [c][kk]: hi/lo of W[h*64+kk][c].
// For Wm2 (128x40, padded to 48 cols): image [c][k]: hi/lo of Wm2[k][c].

__device__ __forceinline__ short f2bf(float v) {
  unsigned u = __float_as_uint(v);
  unsigned r = (u + 0x7FFFu + ((u >> 16) & 1u)) >> 16;
  return (short)r;
}
__device__ __forceinline__ float bf2f(short s) {
  return __uint_as_float(((unsigned)(unsigned short)s) << 16);
}

__global__ __launch_bounds__(256) void k_prep(const float* __restrict__ W1,
                                              const float* __restrict__ W2,
                                              const float* __restrict__ W3,
                                              const float* __restrict__ Wm1,
                                              const float* __restrict__ Wm2,
                                              short* __restrict__ wsplit,
                                              short* __restrict__ w2hi,
                                              short* __restrict__ w2lo) {
  int idx = blockIdx.x * 256 + threadIdx.x;
  if (idx < 65536) {
    int w = idx >> 14;            // which weight
    int rem = idx & 16383;        // h*8192 + c*64 + kk
    int h = rem >> 13;
    int r2 = rem & 8191;
    int c = r2 >> 6, kk = r2 & 63;
    const float* Ws = (w == 0) ? W1 : (w == 1) ? W2 : (w == 2) ? W3 : Wm1;
    float v = Ws[(h * 64 + kk) * D + c];
    short hi = f2bf(v);
    short lo = f2bf(v - bf2f(hi));
    wsplit[(size_t)w * 32768 + rem] = hi;
    wsplit[(size_t)w * 32768 + 16384 + rem] = lo;
  } else if (idx < 65536 + 6144) {
    int i2 = idx - 65536;         // c*128 + k, c in 0..47
    int c = i2 >> 7, k = i2 & 127;
    float v = (c < 40) ? Wm2[k * 40 + c] : 0.f;
    short hi = f2bf(v);
    short lo = f2bf(v - bf2f(hi));
    w2hi[i2] = hi;
    w2lo[i2] = lo;
  }
}

// ---------------- bf16x4-split MFMA GEMM: Y = X @ W (+bias, +ELU) ----------------
// Pre-split W images loaded by plain short8 copies into padded LDS.

__device__ __forceinline__ float elu1(float x) {
  return x > 0.f ? x : (expf(x) - 1.f);
}

__global__ __launch_bounds__(256, 2) void k_gemm(const float* __restrict__ X,
                                                 const short* __restrict__ Whi,
                                                 const short* __restrict__ Wlo,
                                                 const float* __restrict__ bias,
                                                 float* __restrict__ Y, int n, int act) {
  __shared__ short wthi[128 * 72];  // [c][kk-half], padded stride 72
  __shared__ short wtlo[128 * 72];

  int tid = threadIdx.x;
  int wave = tid >> 6, lane = tid & 63;
  int q = lane >> 4, r = lane & 15;

  long rowbase = (long)blockIdx.x * 128 + wave * 32;
  long row0 = rowbase + r;
  long row1 = rowbase + 16 + r;
  long rc0 = row0 < n ? row0 : (n - 1);
  long rc1 = row1 < n ? row1 : (n - 1);
  const floatx4* x0 = (const floatx4*)(X + rc0 * D);
  const floatx4* x1 = (const floatx4*)(X + rc1 * D);

  floatx4 acc[2][8];
#pragma unroll
  for (int rt = 0; rt < 2; rt++)
#pragma unroll
    for (int ct = 0; ct < 8; ct++) acc[rt][ct] = (floatx4){0.f, 0.f, 0.f, 0.f};

  for (int h = 0; h < 2; h++) {
    __syncthreads();
    // copy pre-split half (8192 shorts = 1024 short8) into padded LDS
    const short8* sh = (const short8*)(Whi + h * 8192);
    const short8* sl = (const short8*)(Wlo + h * 8192);
#pragma unroll
    for (int i = 0; i < 4; i++) {
      int cs = i * 256 + tid;           // short8 chunk: c = cs>>3, off = (cs&7)*8
      int c = cs >> 3, o = (cs & 7) * 8;
      *(short8*)&wthi[c * 72 + o] = sh[cs];
      *(short8*)&wtlo[c * 72 + o] = sl[cs];
    }
    __syncthreads();

#pragma unroll
    for (int ks = 0; ks < 2; ks++) {
      int kk0 = ks * 32;
      int xi = h * 16 + kk0 / 4 + q * 2;
      floatx4 a0 = x0[xi], a0b = x0[xi + 1];
      floatx4 a1 = x1[xi], a1b = x1[xi + 1];
      short8 ahi0, alo0, ahi1, alo1;
#pragma unroll
      for (int j = 0; j < 4; j++) {
        float v = a0[j];  short hi = f2bf(v);
        ahi0[j] = hi; alo0[j] = f2bf(v - bf2f(hi));
        v = a0b[j]; hi = f2bf(v);
        ahi0[4 + j] = hi; alo0[4 + j] = f2bf(v - bf2f(hi));
        v = a1[j];  hi = f2bf(v);
        ahi1[j] = hi; alo1[j] = f2bf(v - bf2f(hi));
        v = a1b[j]; hi = f2bf(v);
        ahi1[4 + j] = hi; alo1[4 + j] = f2bf(v - bf2f(hi));
      }
#pragma unroll
      for (int ct = 0; ct < 8; ct++) {
        int c = ct * 16 + r;
        short8 bh = *(const short8*)&wthi[c * 72 + kk0 + q * 8];
        short8 bl = *(const short8*)&wtlo[c * 72 + kk0 + q * 8];
        acc[0][ct] = __builtin_amdgcn_mfma_f32_16x16x32_bf16(ahi0, bh, acc[0][ct], 0, 0, 0);
        acc[0][ct] = __builtin_amdgcn_mfma_f32_16x16x32_bf16(ahi0, bl, acc[0][ct], 0, 0, 0);
        acc[0][ct] = __builtin_amdgcn_mfma_f32_16x16x32_bf16(alo0, bh, acc[0][ct], 0, 0, 0);
        acc[0][ct] = __builtin_amdgcn_mfma_f32_16x16x32_bf16(alo0, bl, acc[0][ct], 0, 0, 0);
        acc[1][ct] = __builtin_amdgcn_mfma_f32_16x16x32_bf16(ahi1, bh, acc[1][ct], 0, 0, 0);
        acc[1][ct] = __builtin_amdgcn_mfma_f32_16x16x32_bf16(ahi1, bl, acc[1][ct], 0, 0, 0);
        acc[1][ct] = __builtin_amdgcn_mfma_f32_16x16x32_bf16(alo1, bh, acc[1][ct], 0, 0, 0);
        acc[1][ct] = __builtin_amdgcn_mfma_f32_16x16x32_bf16(alo1, bl, acc[1][ct], 0, 0, 0);
      }
    }
  }

  // epilogue: C/D layout col = lane&15, row = q*4 + reg
#pragma unroll
  for (int rt = 0; rt < 2; rt++) {
#pragma unroll
    for (int i = 0; i < 4; i++) {
      long row = rowbase + rt * 16 + q * 4 + i;
      if (row < n) {
#pragma unroll
        for (int ct = 0; ct < 8; ct++) {
          int col = ct * 16 + r;
          float v = acc[rt][ct][i];
          if (bias) v += bias[col];
          if (act == 1) v = elu1(v);
          Y[row * D + col] = v;
        }
      }
    }
  }
}

// ---------------- aggregation ----------------
// one wave per node, float2 per lane, edge loop unrolled x8 (8 gathers in flight)

__global__ __launch_bounds__(256) void k_agg(const float* __restrict__ T,
                                             const int* __restrict__ rowptr,
                                             const int* __restrict__ counts,
                                             const int* __restrict__ csrc,
                                             const float* __restrict__ cnorm,
                                             const float* __restrict__ dis,
                                             const float* __restrict__ bias,
                                             float* __restrict__ Y, int n) {
  int node = blockIdx.x * 4 + (threadIdx.x >> 6);
  if (node >= n) return;
  int lane = threadIdx.x & 63;
  const float2* T2 = (const float2*)T;

  int s = rowptr[node];
  int e = s + counts[node];
  float dv = dis[node];
  float2 t = T2[(size_t)node * 64 + lane];
  float ax = t.x * (dv * dv), ay = t.y * (dv * dv);
  float bx2 = 0.f, by2 = 0.f, cx = 0.f, cy = 0.f, dx = 0.f, dy = 0.f;

  int j = s;
  for (; j + 7 < e; j += 8) {
    int s0 = csrc[j],     s1 = csrc[j + 1], s2 = csrc[j + 2], s3 = csrc[j + 3];
    int s4 = csrc[j + 4], s5 = csrc[j + 5], s6 = csrc[j + 6], s7 = csrc[j + 7];
    float n0 = cnorm[j],     n1 = cnorm[j + 1], n2 = cnorm[j + 2], n3 = cnorm[j + 3];
    float n4 = cnorm[j + 4], n5 = cnorm[j + 5], n6 = cnorm[j + 6], n7 = cnorm[j + 7];
    float2 v0 = T2[(size_t)s0 * 64 + lane];
    float2 v1 = T2[(size_t)s1 * 64 + lane];
    float2 v2 = T2[(size_t)s2 * 64 + lane];
    float2 v3 = T2[(size_t)s3 * 64 + lane];
    float2 v4 = T2[(size_t)s4 * 64 + lane];
    float2 v5 = T2[(size_t)s5 * 64 + lane];
    float2 v6 = T2[(size_t)s6 * 64 + lane];
    float2 v7 = T2[(size_t)s7 * 64 + lane];
    ax  += v0.x * n0; ay  += v0.y * n0;
    bx2 += v1.x * n1; by2 += v1.y * n1;
    cx  += v2.x * n2; cy  += v2.y * n2;
    dx  += v3.x * n3; dy  += v3.y * n3;
    ax  += v4.x * n4; ay  += v4.y * n4;
    bx2 += v5.x * n5; by2 += v5.y * n5;
    cx  += v6.x * n6; cy  += v6.y * n6;
    dx  += v7.x * n7; dy  += v7.y * n7;
  }
  for (; j + 3 < e; j += 4) {
    int s0 = csrc[j], s1 = csrc[j + 1], s2 = csrc[j + 2], s3 = csrc[j + 3];
    float n0 = cnorm[j], n1 = cnorm[j + 1], n2 = cnorm[j + 2], n3 = cnorm[j + 3];
    float2 v0 = T2[(size_t)s0 * 64 + lane];
    float2 v1 = T2[(size_t)s1 * 64 + lane];
    float2 v2 = T2[(size_t)s2 * 64 + lane];
    float2 v3 = T2[(size_t)s3 * 64 + lane];
    ax  += v0.x * n0; ay  += v0.y * n0;
    bx2 += v1.x * n1; by2 += v1.y * n1;
    cx  += v2.x * n2; cy  += v2.y * n2;
    dx  += v3.x * n3; dy  += v3.y * n3;
  }
  for (; j < e; ++j) {
    int s0 = csrc[j];
    float n0 = cnorm[j];
    float2 v0 = T2[(size_t)s0 * 64 + lane];
    ax += v0.x * n0; ay += v0.y * n0;
  }

  const float2* b2p = (const float2*)bias;
  float2 bb = b2p[lane];
  float rx = (ax + bx2) + (cx + dx) + bb.x;
  float ry = (ay + by2) + (cy + dy) + bb.y;
  float2 o;
  o.x = fmaxf(rx, 0.f);
  o.y = fmaxf(ry, 0.f);
  *(float2*)&Y[(size_t)node * D + lane * 2] = o;
}

// ---------------- MLP head: MFMA GEMM (128->48 cols, 40 valid) + fused softmax ----
// Block 256 = 4 waves; wave owns 32 rows (2 row-tiles). B frags direct from global.

__global__ __launch_bounds__(256) void k_head(const float* __restrict__ M,
                                              const short* __restrict__ Whi,
                                              const short* __restrict__ Wlo,
                                              const float* __restrict__ b,
                                              float* __restrict__ logits,
                                              float* __restrict__ probs, int n) {
  int tid = threadIdx.x;
  int wave = tid >> 6, lane = tid & 63;
  int q = lane >> 4, r = lane & 15;

  long rowbase = (long)blockIdx.x * 128 + wave * 32;
  long row0 = rowbase + r;
  long row1 = rowbase + 16 + r;
  long rc0 = row0 < n ? row0 : (n - 1);
  long rc1 = row1 < n ? row1 : (n - 1);
  const floatx4* x0 = (const floatx4*)(M + rc0 * D);
  const floatx4* x1 = (const floatx4*)(M + rc1 * D);

  floatx4 acc[2][3];
#pragma unroll
  for (int rt = 0; rt < 2; rt++)
#pragma unroll
    for (int ct = 0; ct < 3; ct++) acc[rt][ct] = (floatx4){0.f, 0.f, 0.f, 0.f};

#pragma unroll
  for (int ks = 0; ks < 4; ks++) {
    int xi = ks * 8 + q * 2;
    floatx4 a0 = x0[xi], a0b = x0[xi + 1];
    floatx4 a1 = x1[xi], a1b = x1[xi + 1];
    short8 ahi0, alo0, ahi1, alo1;
#pragma unroll
    for (int j = 0; j < 4; j++) {
      float v = a0[j];  short hi = f2bf(v);
      ahi0[j] = hi; alo0[j] = f2bf(v - bf2f(hi));
      v = a0b[j]; hi = f2bf(v);
      ahi0[4 + j] = hi; alo0[4 + j] = f2bf(v - bf2f(hi));
      v = a1[j];  hi = f2bf(v);
      ahi1[j] = hi; alo1[j] = f2bf(v - bf2f(hi));
      v = a1b[j]; hi = f2bf(v);
      ahi1[4 + j] = hi; alo1[4 + j] = f2bf(v - bf2f(hi));
    }
#pragma unroll
    for (int ct = 0; ct < 3; ct++) {
      int c = ct * 16 + r;
      short8 bh = *(const short8*)&Whi[c * D + ks * 32 + q * 8];
      short8 bl = *(const short8*)&Wlo[c * D + ks * 32 + q * 8];
      acc[0][ct] = __builtin_amdgcn_mfma_f32_16x16x32_bf16(ahi0, bh, acc[0][ct], 0, 0, 0);
      acc[0][ct] = __builtin_amdgcn_mfma_f32_16x16x32_bf16(ahi0, bl, acc[0][ct], 0, 0, 0);
      acc[0][ct] = __builtin_amdgcn_mfma_f32_16x16x32_bf16(alo0, bh, acc[0][ct], 0, 0, 0);
      acc[0][ct] = __builtin_amdgcn_mfma_f32_16x16x32_bf16(alo0, bl, acc[0][ct], 0, 0, 0);
      acc[1][ct] = __builtin_amdgcn_mfma_f32_16x16x32_bf16(ahi1, bh, acc[1][ct], 0, 0, 0);
      acc[1][ct] = __builtin_amdgcn_mfma_f32_16x16x32_bf16(ahi1, bl, acc[1][ct], 0, 0, 0);
      acc[1][ct] = __builtin_amdgcn_mfma_f32_16x16x32_bf16(alo1, bh, acc[1][ct], 0, 0, 0);
      acc[1][ct] = __builtin_amdgcn_mfma_f32_16x16x32_bf16(alo1, bl, acc[1][ct], 0, 0, 0);
    }
  }

  float bb0 = b[r];
  float bb1 = b[16 + r];
  float bb2 = (r < 8) ? b[32 + r] : 0.f;

#pragma unroll
  for (int rt = 0; rt < 2; rt++) {
#pragma unroll
    for (int i = 0; i < 4; i++) {
      long row = rowbase + rt * 16 + q * 4 + i;
      float v0 = acc[rt][0][i] + bb0;
      float v1 = acc[rt][1][i] + bb1;
      float v2 = (r < 8) ? (acc[rt][2][i] + bb2) : -INFINITY;
      float mx = fmaxf(fmaxf(v0, v1), v2);
      mx = fmaxf(mx, __shfl_xor(mx, 1));
      mx = fmaxf(mx, __shfl_xor(mx, 2));
      mx = fmaxf(mx, __shfl_xor(mx, 4));
      mx = fmaxf(mx, __shfl_xor(mx, 8));
      float e0 = expf(v0 - mx);
      float e1 = expf(v1 - mx);
      float e2 = (r < 8) ? expf(v2 - mx) : 0.f;
      float sm = e0 + e1 + e2;
      sm += __shfl_xor(sm, 1);
      sm += __shfl_xor(sm, 2);
      sm += __shfl_xor(sm, 4);
      sm += __shfl_xor(sm, 8);
      float inv = 1.f / sm;
      if (row < n) {
        float* lp = logits + row * 40;
        float* pp = probs + row * 40;
        lp[r] = v0;      pp[r] = e0 * inv;
        lp[16 + r] = v1; pp[16 + r] = e1 * inv;
        if (r < 8) { lp[32 + r] = v2; pp[32 + r] = e2 * inv; }
      }
    }
  }
}

// ---------------- launcher ----------------

extern "C" void kernel_launch(void* const* d_in, const int* in_sizes, int n_in,
                              void* d_out, int out_size, void* d_ws, size_t ws_size,
                              hipStream_t stream) {
  const float* x   = (const float*)d_in[0];
  const int*   ei  = (const int*)d_in[1];
  const float* W1  = (const float*)d_in[2];
  const float* b1  = (const float*)d_in[3];
  const float* W2  = (const float*)d_in[4];
  const float* b2  = (const float*)d_in[5];
  const float* W3  = (const float*)d_in[6];
  const float* b3  = (const float*)d_in[7];
  const float* Wm1 = (const float*)d_in[8];
  const float* bm1 = (const float*)d_in[9];
  const float* Wm2 = (const float*)d_in[10];
  const float* bm2 = (const float*)d_in[11];

  int N = in_sizes[0] / D;
  int E = in_sizes[1] / 2;
  const int* srcp = ei;
  const int* dstp = ei + E;

  char* w = (char*)d_ws;
  auto alloc = [&](size_t bytes) -> char* {
    char* p = w;
    w += (bytes + 255) & ~(size_t)255;
    return p;
  };
  int*   counts = (int*)alloc((size_t)N * 4);
  int*   rowptr = (int*)alloc((size_t)N * 4);
  int*   cursor = (int*)alloc((size_t)N * 4);
  float* dis    = (float*)alloc((size_t)N * 4);
  int*   bsum   = (int*)alloc(1024);
  short* wsplit = (short*)alloc(4 * 32768 * 2);   // 4 weights x (hi+lo 16384 shorts)
  short* w2hi   = (short*)alloc(6144 * 2);
  short* w2lo   = (short*)alloc(6144 * 2);
  int*   csrc   = (int*)alloc((size_t)E * 4);
  float* cnorm  = (float*)alloc((size_t)E * 4);
  float* tmp    = (float*)alloc((size_t)N * D * 4);
  float* hbuf   = (float*)alloc((size_t)N * D * 4);

  float* logits = (float*)d_out;
  float* probs  = logits + (size_t)N * 40;
  float* emb    = probs + (size_t)N * 40;

  // weight pre-split
  k_prep<<<(65536 + 6144 + 255) / 256, 256, 0, stream>>>(W1, W2, W3, Wm1, Wm2,
                                                         wsplit, w2hi, w2lo);
  // CSR build
  k_zero<<<(N + 255) / 256, 256, 0, stream>>>(counts, N);
  k_hist<<<(E + 255) / 256, 256, 0, stream>>>(dstp, counts, E);
  int nb = (N + 1023) / 1024;
  k_scan1<<<nb, 256, 0, stream>>>(counts, rowptr, bsum, N);
  k_scan2<<<1, 256, 0, stream>>>(bsum, nb);
  k_finish<<<(N + 255) / 256, 256, 0, stream>>>(rowptr, cursor, dis, counts, bsum, N);
  k_fill<<<(E + 255) / 256, 256, 0, stream>>>(srcp, dstp, cursor, dis, csrc, cnorm, E);

  int gblocks = (N + 127) / 128;
  int ablocks = (N + 3) / 4;
  const short* Whi1 = wsplit;
  const short* Wlo1 = wsplit + 16384;
  const short* Whi2 = wsplit + 32768;
  const short* Wlo2 = wsplit + 32768 + 16384;
  const short* Whi3 = wsplit + 2 * 32768;
  const short* Wlo3 = wsplit + 2 * 32768 + 16384;
  const short* Whm1 = wsplit + 3 * 32768;
  const short* Wlm1 = wsplit + 3 * 32768 + 16384;

  // layer 1
  k_gemm<<<gblocks, 256, 0, stream>>>(x, Whi1, Wlo1, nullptr, tmp, N, 0);
  k_agg<<<ablocks, 256, 0, stream>>>(tmp, rowptr, counts, csrc, cnorm, dis, b1, hbuf, N);
  // layer 2
  k_gemm<<<gblocks, 256, 0, stream>>>(hbuf, Whi2, Wlo2, nullptr, tmp, N, 0);
  k_agg<<<ablocks, 256, 0, stream>>>(tmp, rowptr, counts, csrc, cnorm, dis, b2, hbuf, N);
  // layer 3 -> emb
  k_gemm<<<gblocks, 256, 0, stream>>>(hbuf, Whi3, Wlo3, nullptr, tmp, N, 0);
  k_agg<<<ablocks, 256, 0, stream>>>(tmp, rowptr, counts, csrc, cnorm, dis, b3, emb, N);
  // MLP head
  k_gemm<<<gblocks, 256, 0, stream>>>(emb, Whm1, Wlm1, bm1, tmp, N, 1);
  k_head<<<gblocks, 256, 0, stream>>>(tmp, w2hi, w2lo, bm2, logits, probs, N);
}